// Round 8
// baseline (77.710 us; speedup 1.0000x reference)
//
#include <hip/hip_runtime.h>
#include <hip/hip_cooperative_groups.h>

namespace cg = cooperative_groups;

// Reference collapses: softmax over a singleton axis == 1, so
//   out[b,c,:,:] = (Wout @ v_b + bout)[c],  v_b = Wkv[C:,:] @ context[b]
// x and Wq are dead. Bound by the 134 MB output write (~19 us at 7.1 TB/s).
//
// R7 lesson: redundant per-block v-compute is latency-bound (~25 us). So:
// ONE cooperative kernel, ONE grid sync. Wave w owns 4 consecutive output
// rows: computes their v entries, grid.sync(), computes their y values
// (wave-local!), then stores 4 x 16 KB — R6's proven saturating store shape.

#define BB   16
#define CC   512
#define CTX  256
#define NN   4096   // H*W

typedef float f32x4 __attribute__((ext_vector_type(4)));

__global__ __launch_bounds__(256) void fused_coop_kernel(
    const float* __restrict__ ctx,   // B x CTX
    const float* __restrict__ Wkv,   // 2C x CTX
    const float* __restrict__ Wout,  // C x C
    const float* __restrict__ bout,  // C
    float* __restrict__ v_ws,        // B*C scratch (d_ws)
    f32x4* __restrict__ out)         // B*C*NN floats
{
    const int wave = threadIdx.x >> 6;                    // 0..3
    const int lane = threadIdx.x & 63;
    const int gw   = (blockIdx.x << 2) + wave;            // 0..2047
    const int r0   = gw << 2;                             // first of 4 rows
    const int b    = r0 >> 9;                             // same b for all 4

    // whole 256-float context row across the wave
    const f32x4 cx = ((const f32x4*)(ctx + b * CTX))[lane];

    // Phase 1: v for rows r0..r0+3  (j = channel index)
    #pragma unroll
    for (int i = 0; i < 4; ++i) {
        const int j = (r0 + i) & (CC - 1);
        const f32x4 wv = ((const f32x4*)(Wkv + (size_t)(CC + j) * CTX))[lane];
        float p = wv.x * cx.x + wv.y * cx.y + wv.z * cx.z + wv.w * cx.w;
        #pragma unroll
        for (int m = 32; m >= 1; m >>= 1) p += __shfl_xor(p, m);
        if (lane == 0) v_ws[r0 + i] = p;
    }

    cg::this_grid().sync();

    // Phase 2+3: y (butterfly sum lands in ALL lanes) then 16 KB splat store.
    const f32x4* vr = (const f32x4*)(v_ws + (size_t)b * CC);
    const f32x4 v0 = vr[lane], v1 = vr[64 + lane];
    #pragma unroll
    for (int i = 0; i < 4; ++i) {
        const int c = (r0 + i) & (CC - 1);
        const f32x4* wr = (const f32x4*)(Wout + (size_t)c * CC);
        const f32x4 w0 = wr[lane], w1 = wr[64 + lane];
        float p = w0.x * v0.x + w0.y * v0.y + w0.z * v0.z + w0.w * v0.w
                + w1.x * v1.x + w1.y * v1.y + w1.z * v1.z + w1.w * v1.w;
        #pragma unroll
        for (int m = 32; m >= 1; m >>= 1) p += __shfl_xor(p, m);
        const float y = p + bout[c];

        f32x4 val; val.x = y; val.y = y; val.z = y; val.w = y;
        f32x4* dst = out + (size_t)(r0 + i) * (NN / 4) + lane;
        #pragma unroll
        for (int j = 0; j < 16; ++j)
            dst[j * 64] = val;
    }
}

extern "C" void kernel_launch(void* const* d_in, const int* in_sizes, int n_in,
                              void* d_out, int out_size, void* d_ws, size_t ws_size,
                              hipStream_t stream) {
    // inputs: 0=x (dead), 1=context, 2=Wq (dead), 3=Wkv, 4=Wout, 5=bout
    const float* context = (const float*)d_in[1];
    const float* Wkv     = (const float*)d_in[3];
    const float* Wout    = (const float*)d_in[4];
    const float* bout    = (const float*)d_in[5];
    float* v_ws = (float*)d_ws;     // B*C floats
    f32x4* out  = (f32x4*)d_out;

    void* args[] = { (void*)&context, (void*)&Wkv, (void*)&Wout,
                     (void*)&bout, (void*)&v_ws, (void*)&out };
    hipLaunchCooperativeKernel((void*)fused_coop_kernel,
                               dim3(512), dim3(256), args, 0, stream);
}

// Round 9
// 44.389 us; speedup vs baseline: 1.7507x; 1.7507x over previous
//
#include <hip/hip_runtime.h>

// Reference collapses: softmax over a singleton axis == 1, so
//   out[b,c,:,:] = (Wout @ v_b + bout)[c],  v_b = Wkv[C:,:] @ context[b]
// x and Wq are dead. Bound by the 134 MB output write.
//
// Single kernel + captured memset. Soft per-batch barrier (manual, NOT
// cooperative API — R8 showed that costs 45 us): 32 blocks/batch produce
// 16 v-entries each, release-count, acquire-spin on the batch counter
// (all 512 blocks co-resident: 256 thr, no LDS, low VGPR). Then y is
// wave-local and stores use R6's proven saturating shape.

#define BB   16
#define CC   512
#define CTX  256
#define NN   4096   // H*W
#define CNT_STRIDE 32  // uints; one 128B cacheline per batch counter

typedef float f32x4 __attribute__((ext_vector_type(4)));

__global__ __launch_bounds__(256) void fused_soft_kernel(
    const float* __restrict__ ctx,   // B x CTX
    const float* __restrict__ Wkv,   // 2C x CTX
    const float* __restrict__ Wout,  // C x C
    const float* __restrict__ bout,  // C
    float* __restrict__ v_ws,        // B*C floats (d_ws)
    unsigned int* __restrict__ cnt,  // BB counters, padded (d_ws + 32KB)
    f32x4* __restrict__ out)
{
    const int wave = threadIdx.x >> 6;           // 0..3
    const int lane = threadIdx.x & 63;
    const int blk  = blockIdx.x;                 // 0..511
    const int b    = blk >> 5;                   // 32 blocks per batch
    const int seg  = blk & 31;                   // this block's 16-row segment
    const int r0   = (b << 9) + (seg << 4);      // first global row

    // whole 256-float context row across the wave
    const f32x4 cx = ((const f32x4*)(ctx + b * CTX))[lane];

    // Phase 1: this block's 16 v entries (wave does 4).
    #pragma unroll
    for (int i = 0; i < 4; ++i) {
        const int j = (seg << 4) + (wave << 2) + i;        // channel 0..511
        const f32x4 wv = ((const f32x4*)(Wkv + (size_t)(CC + j) * CTX))[lane];
        float p = wv.x * cx.x + wv.y * cx.y + wv.z * cx.z + wv.w * cx.w;
        #pragma unroll
        for (int m = 32; m >= 1; m >>= 1) p += __shfl_xor(p, m);
        if (lane == 0) v_ws[(b << 9) + j] = p;
    }
    __syncthreads();

    // Soft per-batch barrier: release our contribution, wait for all 32.
    if (threadIdx.x == 0) {
        __hip_atomic_fetch_add(&cnt[b * CNT_STRIDE], 1u,
                               __ATOMIC_RELEASE, __HIP_MEMORY_SCOPE_AGENT);
        while (__hip_atomic_load(&cnt[b * CNT_STRIDE],
                                 __ATOMIC_ACQUIRE, __HIP_MEMORY_SCOPE_AGENT) < 32u) {
            __builtin_amdgcn_s_sleep(2);
        }
    }
    __syncthreads();

    // Phase 2: y for our 16 rows (wave-local butterfly -> all lanes), store.
    const f32x4* vr = (const f32x4*)(v_ws + ((size_t)b << 9));
    const f32x4 v0 = vr[lane], v1 = vr[64 + lane];
    #pragma unroll
    for (int i = 0; i < 4; ++i) {
        const int cl = (seg << 4) + (wave << 2) + i;       // channel
        const int row = (b << 9) + cl;
        const f32x4* wr = (const f32x4*)(Wout + (size_t)cl * CC);
        const f32x4 w0 = wr[lane], w1 = wr[64 + lane];
        float p = w0.x * v0.x + w0.y * v0.y + w0.z * v0.z + w0.w * v0.w
                + w1.x * v1.x + w1.y * v1.y + w1.z * v1.z + w1.w * v1.w;
        #pragma unroll
        for (int m = 32; m >= 1; m >>= 1) p += __shfl_xor(p, m);
        const float y = p + bout[cl];

        f32x4 val; val.x = y; val.y = y; val.z = y; val.w = y;
        f32x4* dst = out + (size_t)row * (NN / 4) + lane;
        #pragma unroll
        for (int j = 0; j < 16; ++j)
            dst[j * 64] = val;
    }
}

extern "C" void kernel_launch(void* const* d_in, const int* in_sizes, int n_in,
                              void* d_out, int out_size, void* d_ws, size_t ws_size,
                              hipStream_t stream) {
    // inputs: 0=x (dead), 1=context, 2=Wq (dead), 3=Wkv, 4=Wout, 5=bout
    const float* context = (const float*)d_in[1];
    const float* Wkv     = (const float*)d_in[3];
    const float* Wout    = (const float*)d_in[4];
    const float* bout    = (const float*)d_in[5];
    f32x4* out = (f32x4*)d_out;

    float* v_ws = (float*)d_ws;                              // 32 KB
    unsigned int* cnt = (unsigned int*)((char*)d_ws + (size_t)BB * CC * 4);

    // zero the per-batch counters every call (deterministic; capturable)
    hipMemsetAsync(cnt, 0, BB * CNT_STRIDE * sizeof(unsigned int), stream);

    fused_soft_kernel<<<512, 256, 0, stream>>>(context, Wkv, Wout, bout,
                                               v_ws, cnt, out);
}

// Round 10
// 39.879 us; speedup vs baseline: 1.9486x; 1.1131x over previous
//
#include <hip/hip_runtime.h>

// Reference collapses: softmax over singleton axis == 1 =>
//   out[b,c,:,:] = (Wout @ v_b + bout)[c],  v_b = Wkv[C:,:] @ context[b]
// Re-associate to kill the v->y dependency barrier:
//   y_b = M @ ctx_b + bout,  M = Wout @ Wkv_v  (weights-only, 512x256)
// K1: tiny tiled GEMM for M (128 blocks, ~2 us, no cross-block deps).
// K2: per-wave y-dot (M row 1 KB + ctx row 1 KB) + 16 KB splat store.
// 2 kernels, 1 boundary, zero grid sync (R7/R8/R9: all sync forms lose).

#define BB   16
#define CC   512
#define CTX  256
#define NN   4096   // H*W

typedef float f32x4 __attribute__((ext_vector_type(4)));
typedef float f32x2 __attribute__((ext_vector_type(2)));

// K1: M[c,t] = sum_j Wout[c,j] * Wkv[C+j,t].  M row-major 512x256 (d_ws).
// Grid (16,8): 32x32 tile per block, K-sliced by 64, LDS-staged.
__global__ __launch_bounds__(256) void m_kernel(
    const float* __restrict__ Wkv,   // 2C x CTX
    const float* __restrict__ Wout,  // C x C
    float* __restrict__ M)           // C x CTX
{
    __shared__ float a_s[64][36];    // [j][c]  (pad 36: 16B-aligned rows, bank-spread)
    __shared__ float b_s[64][36];    // [j][t]

    const int tid = threadIdx.x;
    const int c0 = blockIdx.x * 32, t0 = blockIdx.y * 32;

    const int lc = tid >> 3;             // 0..31  A-load row
    const int lj = (tid & 7) * 8;        // A-load j-offset
    const int bj = tid >> 2;             // 0..63  B-load j
    const int bt = (tid & 3) * 8;        // B-load t-offset

    const int cy = tid >> 4, tx = tid & 15;
    float acc00 = 0.f, acc01 = 0.f, acc10 = 0.f, acc11 = 0.f;

    for (int jb = 0; jb < CC; jb += 64) {
        const float* ap = Wout + (size_t)(c0 + lc) * CC + jb + lj;
        const f32x4 av0 = ((const f32x4*)ap)[0];
        const f32x4 av1 = ((const f32x4*)ap)[1];
        const float* bp = Wkv + (size_t)(CC + jb + bj) * CTX + t0 + bt;
        const f32x4 bv0 = ((const f32x4*)bp)[0];
        const f32x4 bv1 = ((const f32x4*)bp)[1];

        #pragma unroll
        for (int k = 0; k < 4; ++k) a_s[lj + k][lc]     = av0[k];
        #pragma unroll
        for (int k = 0; k < 4; ++k) a_s[lj + 4 + k][lc] = av1[k];
        *(f32x4*)&b_s[bj][bt]     = bv0;
        *(f32x4*)&b_s[bj][bt + 4] = bv1;
        __syncthreads();

        #pragma unroll 8
        for (int j = 0; j < 64; ++j) {
            const f32x2 a = *(const f32x2*)&a_s[j][cy * 2];
            const f32x2 b = *(const f32x2*)&b_s[j][tx * 2];
            acc00 += a[0] * b[0]; acc01 += a[0] * b[1];
            acc10 += a[1] * b[0]; acc11 += a[1] * b[1];
        }
        __syncthreads();
    }

    float* m0 = M + (size_t)(c0 + cy * 2) * CTX + t0 + tx * 2;
    f32x2 r0; r0[0] = acc00; r0[1] = acc01;
    f32x2 r1; r1[0] = acc10; r1[1] = acc11;
    *(f32x2*)m0        = r0;
    *(f32x2*)(m0 + CTX) = r1;
}

// K2: one wave per output row (b,c): y = dot(M[c,:], ctx[b,:]) + bout[c],
// then 16 coalesced dwordx4 splat stores (16 KB row).
__global__ __launch_bounds__(256) void out_kernel(
    const float* __restrict__ M,     // C x CTX
    const float* __restrict__ ctx,   // B x CTX
    const float* __restrict__ bout,  // C
    f32x4* __restrict__ out)
{
    const int w    = (blockIdx.x << 2) + (threadIdx.x >> 6);  // 0..8191
    const int lane = threadIdx.x & 63;
    const int b    = w >> 9;
    const int c    = w & (CC - 1);

    const f32x4 mv = ((const f32x4*)(M   + (size_t)c * CTX))[lane];
    const f32x4 cx = ((const f32x4*)(ctx + (size_t)b * CTX))[lane];
    float p = mv.x * cx.x + mv.y * cx.y + mv.z * cx.z + mv.w * cx.w;
    #pragma unroll
    for (int m = 32; m >= 1; m >>= 1) p += __shfl_xor(p, m);

    const float y = p + bout[c];
    f32x4 val; val.x = y; val.y = y; val.z = y; val.w = y;
    f32x4* dst = out + (size_t)w * (NN / 4) + lane;
    #pragma unroll
    for (int j = 0; j < 16; ++j)
        dst[j * 64] = val;
}

extern "C" void kernel_launch(void* const* d_in, const int* in_sizes, int n_in,
                              void* d_out, int out_size, void* d_ws, size_t ws_size,
                              hipStream_t stream) {
    // inputs: 0=x (dead), 1=context, 2=Wq (dead), 3=Wkv, 4=Wout, 5=bout
    const float* context = (const float*)d_in[1];
    const float* Wkv     = (const float*)d_in[3];
    const float* Wout    = (const float*)d_in[4];
    const float* bout    = (const float*)d_in[5];
    f32x4* out = (f32x4*)d_out;
    float* M   = (float*)d_ws;        // 512 KB

    m_kernel<<<dim3(16, 8), 256, 0, stream>>>(Wkv, Wout, M);
    out_kernel<<<2048, 256, 0, stream>>>(M, context, bout, out);
}

// Round 11
// 31.519 us; speedup vs baseline: 2.4655x; 1.2653x over previous
//
#include <hip/hip_runtime.h>

// Reference collapses: softmax over singleton axis == 1 =>
//   out[b,c,:,:] = (Wout @ v_b + bout)[c],  v_b = Wkv[C:,:] @ context[b]
// x, Wq dead. Bound by the 134 MB output write (~19-20 us @ ~7 TB/s).
//
// R11: K1 = proven wave-per-(b,j) v GEMV. K2 = store kernel organized as
// wave = (channel c, 8 batches): Wout[c,:] read ONCE total (1 MB aggregate,
// vs 16 MB in per-(b,c) schemes), v rows come from a 32 KB L2-hot table,
// 8 y-dots in registers, then a dense 128-store phase (8 rows x 16 KB).

#define BB   16
#define CC   512
#define CTX  256
#define NN   4096   // H*W

typedef float f32x4 __attribute__((ext_vector_type(4)));

// K1: v[b*C+j] = dot(Wkv[C+j,:], ctx[b,:]).  One wave per (b,j). 2048 blocks.
__global__ __launch_bounds__(256) void v_kernel(
    const float* __restrict__ ctx,   // B x CTX
    const float* __restrict__ Wkv,   // 2C x CTX
    float* __restrict__ v)           // B*C (d_ws)
{
    const int w    = (blockIdx.x << 2) + (threadIdx.x >> 6);  // 0..8191
    const int lane = threadIdx.x & 63;
    const int b    = w >> 9;          // /C
    const int j    = w & (CC - 1);

    const f32x4 cx = ((const f32x4*)(ctx + b * CTX))[lane];
    const f32x4 wv = ((const f32x4*)(Wkv + (size_t)(CC + j) * CTX))[lane];
    float p = wv.x * cx.x + wv.y * cx.y + wv.z * cx.z + wv.w * cx.w;
    #pragma unroll
    for (int m = 32; m >= 1; m >>= 1) p += __shfl_xor(p, m);
    if (lane == 0) v[w] = p;
}

// K2: wave = (c, batch-group). 256 blocks x 256 thr = 1024 waves.
// Wave wid: c = wid>>1, batches b0..b0+7 where b0 = (wid&1)*8.
__global__ __launch_bounds__(256) void out_kernel(
    const float* __restrict__ v,     // B*C (L2-hot, 32 KB)
    const float* __restrict__ Wout,  // C x C
    const float* __restrict__ bout,  // C
    f32x4* __restrict__ out)
{
    const int wid  = (blockIdx.x << 2) + (threadIdx.x >> 6);  // 0..1023
    const int lane = threadIdx.x & 63;
    const int c    = wid >> 1;
    const int b0   = (wid & 1) << 3;

    const f32x4* wr = (const f32x4*)(Wout + (size_t)c * CC);
    const f32x4 w0 = wr[lane], w1 = wr[64 + lane];
    const float bb = bout[c];

    // 8 y-dots: v rows are L2-hot (32 KB table shared by all waves)
    float yv[8];
    #pragma unroll
    for (int i = 0; i < 8; ++i) {
        const f32x4* vr = (const f32x4*)(v + (size_t)(b0 + i) * CC);
        const f32x4 v0 = vr[lane], v1 = vr[64 + lane];
        float p = w0.x * v0.x + w0.y * v0.y + w0.z * v0.z + w0.w * v0.w
                + w1.x * v1.x + w1.y * v1.y + w1.z * v1.z + w1.w * v1.w;
        #pragma unroll
        for (int m = 32; m >= 1; m >>= 1) p += __shfl_xor(p, m);
        yv[i] = p + bb;
    }

    // dense store phase: 8 rows x 16 KB, 128 dwordx4 stores per lane
    #pragma unroll
    for (int i = 0; i < 8; ++i) {
        const int row = ((b0 + i) << 9) + c;          // b*C + c
        f32x4 val; val.x = yv[i]; val.y = yv[i]; val.z = yv[i]; val.w = yv[i];
        f32x4* dst = out + (size_t)row * (NN / 4) + lane;
        #pragma unroll
        for (int j = 0; j < 16; ++j)
            dst[j * 64] = val;
    }
}

extern "C" void kernel_launch(void* const* d_in, const int* in_sizes, int n_in,
                              void* d_out, int out_size, void* d_ws, size_t ws_size,
                              hipStream_t stream) {
    // inputs: 0=x (dead), 1=context, 2=Wq (dead), 3=Wkv, 4=Wout, 5=bout
    const float* context = (const float*)d_in[1];
    const float* Wkv     = (const float*)d_in[3];
    const float* Wout    = (const float*)d_in[4];
    const float* bout    = (const float*)d_in[5];
    f32x4* out = (f32x4*)d_out;
    float* v   = (float*)d_ws;   // 32 KB

    v_kernel<<<2048, 256, 0, stream>>>(context, Wkv, v);
    out_kernel<<<256, 256, 0, stream>>>(v, Wout, bout, out);
}